// Round 1
// baseline (450.388 us; speedup 1.0000x reference)
//
#include <hip/hip_runtime.h>
#include <math.h>

#define NCELL 125000
#define KNBR  26
#define D     32

__device__ __forceinline__ float fast_tanh(float x) {
    // tanh(x) = 1 - 2/(exp(2x)+1); exact at +/-inf, ~1e-7 rel error
    float e = __expf(2.0f * x);
    return 1.0f - 2.0f / (e + 1.0f);
}

// ---------------- kernel 1: per-cell message precompute ----------------
// M[c][d] = tanh( sum_j X[c][j] * Wm[j][d] + bm[d] )
__global__ void __launch_bounds__(256) msg_kernel(
    const float* __restrict__ X, const float* __restrict__ Wm,
    const float* __restrict__ bm, float* __restrict__ M)
{
    int t = blockIdx.x * 256 + threadIdx.x;
    int c = t >> 5, d = t & 31;
    if (c >= NCELL) return;
    const float* x = X + (size_t)c * D;
    float acc = bm[d];
#pragma unroll
    for (int j = 0; j < D; ++j)
        acc = fmaf(x[j], Wm[j * D + d], acc);
    M[(size_t)c * D + d] = fast_tanh(acc);
}

// ---------------- kernel 2: neighbor gather + tier means ----------------
// aggs[c] = [ local_agg(32) | func_agg(32) | dist_agg(32) | func_msg(32) ]
__global__ void __launch_bounds__(256) agg_kernel(
    const float* __restrict__ X, const float* __restrict__ M,
    const int* __restrict__ nbr, const int* __restrict__ tier,
    float* __restrict__ aggs)
{
    int t = blockIdx.x * 256 + threadIdx.x;
    int c = t >> 5, d = t & 31;
    if (c >= NCELL) return;
    float s0 = 0.f, s1 = 0.f, s2 = 0.f, sm = 0.f;
    int c0 = 0, c1 = 0, c2 = 0;
    const int* nb = nbr + c * KNBR;
    const int* tr = tier + c * KNBR;
#pragma unroll 2
    for (int k = 0; k < KNBR; ++k) {
        int j  = nb[k];
        int tt = tr[k];
        float x = X[(size_t)j * D + d];
        if (tt == 0)      { s0 += x; c0++; }
        else if (tt == 1) { s1 += x; c1++; sm += M[(size_t)j * D + d]; }
        else              { s2 += x; c2++; }
    }
    float* a = aggs + (size_t)c * 4 * D + d;
    a[0 * D] = s0 / fmaxf((float)c0, 1.f);
    a[1 * D] = s1 / fmaxf((float)c1, 1.f);
    a[2 * D] = s2 / fmaxf((float)c2, 1.f);
    a[3 * D] = sm / fmaxf((float)c1, 1.f);
}

// acc[d] += sum_{j<32} in[j] * W[j*D+d]   (in: per-thread memory row; W: uniform -> s_load)
__device__ __forceinline__ void matvec32(const float* __restrict__ in,
                                         const float* __restrict__ W,
                                         float acc[D])
{
#pragma unroll 8
    for (int j = 0; j < D; ++j) {
        float v = in[j];
#pragma unroll
        for (int d = 0; d < D; ++d)
            acc[d] = fmaf(v, W[j * D + d], acc[d]);
    }
}

// ---------------- kernel 3: experts + gate, one thread per cell ----------------
__global__ void __launch_bounds__(256) expert_kernel(
    const float* __restrict__ X, const float* __restrict__ aggs,
    const float* __restrict__ Wl, const float* __restrict__ bl,
    const float* __restrict__ Wf, const float* __restrict__ bf,
    const float* __restrict__ Wc, const float* __restrict__ bc,
    const float* __restrict__ Wg, const float* __restrict__ bg,
    float* __restrict__ out)
{
    int c = blockIdx.x * 256 + threadIdx.x;
    if (c >= NCELL) return;
    const float* xr = X    + (size_t)c * D;       // cur
    const float* ar = aggs + (size_t)c * 4 * D;   // la | fa | da | fm

    // ---- gate: softmax([cur;la;fa;da] @ Wg + bg) ----
    float g0 = bg[0], g1 = bg[1], g2 = bg[2];
    {
        const float* ins[4] = { xr, ar, ar + D, ar + 2 * D };
#pragma unroll
        for (int b = 0; b < 4; ++b) {
            const float* in = ins[b];
#pragma unroll 8
            for (int j = 0; j < D; ++j) {
                float v = in[j];
                g0 = fmaf(v, Wg[(b * D + j) * 3 + 0], g0);
                g1 = fmaf(v, Wg[(b * D + j) * 3 + 1], g1);
                g2 = fmaf(v, Wg[(b * D + j) * 3 + 2], g2);
            }
        }
    }
    float mx = fmaxf(g0, fmaxf(g1, g2));
    float e0 = __expf(g0 - mx), e1 = __expf(g1 - mx), e2 = __expf(g2 - mx);
    float inv = 1.f / (e0 + e1 + e2);
    float w0 = e0 * inv, w1 = e1 * inv, w2 = e2 * inv;

    float acc[D], o[D];

    // ---- local expert: tanh([cur ; la] @ Wl + bl) ----
#pragma unroll
    for (int d = 0; d < D; ++d) acc[d] = bl[d];
    matvec32(xr, Wl, acc);
    matvec32(ar, Wl + D * D, acc);
#pragma unroll
    for (int d = 0; d < D; ++d) o[d] = w0 * fast_tanh(acc[d]);

    // ---- functional expert: tanh([cur ; fm] @ Wf + bf) ----
#pragma unroll
    for (int d = 0; d < D; ++d) acc[d] = bf[d];
    matvec32(xr, Wf, acc);
    matvec32(ar + 3 * D, Wf + D * D, acc);
#pragma unroll
    for (int d = 0; d < D; ++d) o[d] = fmaf(w1, fast_tanh(acc[d]), o[d]);

    // ---- distant expert: 3-step explicit Euler CNF ----
    // dist-half contribution is step-invariant: gc = bc + da @ Wc[32:64]
    float gc[D];
#pragma unroll
    for (int d = 0; d < D; ++d) gc[d] = bc[d];
    matvec32(ar + 2 * D, Wc + D * D, gc);

    float xx[D];
#pragma unroll
    for (int d = 0; d < D; ++d) xx[d] = xr[d];

    const float dt = 1.0f / 3.0f;
#pragma unroll 1
    for (int s = 0; s < 3; ++s) {
        float a2[D];
#pragma unroll
        for (int d = 0; d < D; ++d) a2[d] = gc[d];
#pragma unroll
        for (int j = 0; j < D; ++j) {
            float v = xx[j];
#pragma unroll
            for (int d = 0; d < D; ++d)
                a2[d] = fmaf(v, Wc[j * D + d], a2[d]);
        }
#pragma unroll
        for (int d = 0; d < D; ++d)
            xx[d] += dt * fast_tanh(a2[d]);
    }
#pragma unroll
    for (int d = 0; d < D; ++d) o[d] = fmaf(w2, xx[d], o[d]);

#pragma unroll
    for (int d = 0; d < D; ++d) out[(size_t)c * D + d] = o[d];
}

extern "C" void kernel_launch(void* const* d_in, const int* in_sizes, int n_in,
                              void* d_out, int out_size, void* d_ws, size_t ws_size,
                              hipStream_t stream)
{
    const float* X    = (const float*)d_in[0];
    const int*   nbr  = (const int*)  d_in[1];
    const int*   tier = (const int*)  d_in[2];
    const float* Wl   = (const float*)d_in[3];
    const float* bl   = (const float*)d_in[4];
    const float* Wm   = (const float*)d_in[5];
    const float* bm   = (const float*)d_in[6];
    const float* Wf   = (const float*)d_in[7];
    const float* bf   = (const float*)d_in[8];
    const float* Wc   = (const float*)d_in[9];
    const float* bc   = (const float*)d_in[10];
    const float* Wg   = (const float*)d_in[11];
    const float* bg   = (const float*)d_in[12];
    float* out = (float*)d_out;

    float* M    = (float*)d_ws;                    // [NCELL][D]
    float* aggs = M + (size_t)NCELL * D;           // [NCELL][4][D]

    int nt = NCELL * D;
    dim3 blk(256);
    msg_kernel<<<dim3((nt + 255) / 256), blk, 0, stream>>>(X, Wm, bm, M);
    agg_kernel<<<dim3((nt + 255) / 256), blk, 0, stream>>>(X, M, nbr, tier, aggs);
    expert_kernel<<<dim3((NCELL + 255) / 256), blk, 0, stream>>>(
        X, aggs, Wl, bl, Wf, bf, Wc, bc, Wg, bg, out);
}

// Round 2
// 286.479 us; speedup vs baseline: 1.5722x; 1.5722x over previous
//
#include <hip/hip_runtime.h>
#include <math.h>

#define NCELL 125000
#define KNBR  26
#define D     32

__device__ __forceinline__ float fast_tanh(float x) {
    // tanh(x) = 1 - 2/(exp(2x)+1); exact at +/-inf, ~1e-7 rel error
    float e = __expf(2.0f * x);
    return 1.0f - 2.0f / (e + 1.0f);
}

// ---------------- kernel 1: per-cell message precompute ----------------
// M[c][d] = tanh( sum_j X[c][j] * Wm[j][d] + bm[d] )
__global__ void __launch_bounds__(256) msg_kernel(
    const float* __restrict__ X, const float* __restrict__ Wm,
    const float* __restrict__ bm, float* __restrict__ M)
{
    int t = blockIdx.x * 256 + threadIdx.x;
    int c = t >> 5, d = t & 31;
    if (c >= NCELL) return;
    const float* x = X + (size_t)c * D;
    float acc = bm[d];
#pragma unroll
    for (int j = 0; j < D; ++j)
        acc = fmaf(x[j], Wm[j * D + d], acc);
    M[(size_t)c * D + d] = fast_tanh(acc);
}

// ---------------- kernel 2: gather + tier means + GATE ----------------
// aggs[c] = [ local_agg(32) | func_msg(32) | dist_agg(32) ]   (func_agg only feeds gate)
// wgt[c]  = softmax gate weights (3 floats, padded to 4)
__global__ void __launch_bounds__(256) agg_gate_kernel(
    const float* __restrict__ X, const float* __restrict__ M,
    const int* __restrict__ nbr, const int* __restrict__ tier,
    const float* __restrict__ Wg, const float* __restrict__ bg,
    float* __restrict__ aggs, float* __restrict__ wgt)
{
    int t = blockIdx.x * 256 + threadIdx.x;
    int c = t >> 5, d = t & 31;
    if (c >= NCELL) return;

    // coalesced index/tier load: lane k<26 owns (idx,tier) pair k, broadcast via shfl
    int my_idx = 0, my_t = 3;
    if (d < KNBR) {
        my_idx = nbr[c * KNBR + d];
        my_t   = tier[c * KNBR + d];
    }

    float s0 = 0.f, s1 = 0.f, s2 = 0.f, sm = 0.f;
    float n0 = 0.f, n1 = 0.f, n2 = 0.f;
#pragma unroll
    for (int k = 0; k < KNBR; ++k) {
        int j  = __shfl(my_idx, k, 32);
        int tt = __shfl(my_t,  k, 32);
        float x = X[j * D + d];
        bool t0 = (tt == 0), t1 = (tt == 1), t2 = (tt == 2);
        s0 += t0 ? x : 0.f;   n0 += t0 ? 1.f : 0.f;
        s1 += t1 ? x : 0.f;   n1 += t1 ? 1.f : 0.f;
        s2 += t2 ? x : 0.f;   n2 += t2 ? 1.f : 0.f;
        if (t1) sm += M[j * D + d];   // uniform branch per 32-group
    }
    float la = s0 / fmaxf(n0, 1.f);
    float fa = s1 / fmaxf(n1, 1.f);
    float da = s2 / fmaxf(n2, 1.f);
    float fm = sm / fmaxf(n1, 1.f);

    float* a = aggs + (size_t)c * 3 * D + d;
    a[0 * D] = la;
    a[1 * D] = fm;
    a[2 * D] = da;

    // ---- gate: per-lane partial dot, butterfly reduce over the 32-group ----
    float x = X[c * D + d];
    float g0 = 0.f, g1 = 0.f, g2 = 0.f;
    g0 = fmaf(x,  Wg[(0 * D + d) * 3 + 0], g0);
    g1 = fmaf(x,  Wg[(0 * D + d) * 3 + 1], g1);
    g2 = fmaf(x,  Wg[(0 * D + d) * 3 + 2], g2);
    g0 = fmaf(la, Wg[(1 * D + d) * 3 + 0], g0);
    g1 = fmaf(la, Wg[(1 * D + d) * 3 + 1], g1);
    g2 = fmaf(la, Wg[(1 * D + d) * 3 + 2], g2);
    g0 = fmaf(fa, Wg[(2 * D + d) * 3 + 0], g0);
    g1 = fmaf(fa, Wg[(2 * D + d) * 3 + 1], g1);
    g2 = fmaf(fa, Wg[(2 * D + d) * 3 + 2], g2);
    g0 = fmaf(da, Wg[(3 * D + d) * 3 + 0], g0);
    g1 = fmaf(da, Wg[(3 * D + d) * 3 + 1], g1);
    g2 = fmaf(da, Wg[(3 * D + d) * 3 + 2], g2);
#pragma unroll
    for (int m = 16; m >= 1; m >>= 1) {
        g0 += __shfl_xor(g0, m, 32);
        g1 += __shfl_xor(g1, m, 32);
        g2 += __shfl_xor(g2, m, 32);
    }
    g0 += bg[0]; g1 += bg[1]; g2 += bg[2];
    float mx = fmaxf(g0, fmaxf(g1, g2));
    float e0 = __expf(g0 - mx), e1 = __expf(g1 - mx), e2 = __expf(g2 - mx);
    float inv = 1.f / (e0 + e1 + e2);
    if (d < 3) {
        float w = (d == 0 ? e0 : (d == 1 ? e1 : e2)) * inv;
        wgt[c * 4 + d] = w;
    }
}

// acc[d] += sum_{j<32} in[j] * W[j*D+d]   (W wave-uniform -> s_load, SGPR operand)
__device__ __forceinline__ void matvec32(const float* __restrict__ in,
                                         const float* __restrict__ W,
                                         float acc[D])
{
#pragma unroll 8
    for (int j = 0; j < D; ++j) {
        float v = in[j];
#pragma unroll
        for (int d = 0; d < D; ++d)
            acc[d] = fmaf(v, W[j * D + d], acc[d]);
    }
}

// ---------------- kernel 3: experts, thread-per-cell, blockIdx.y = expert ----------------
__global__ void __launch_bounds__(256) expert_kernel(
    const float* __restrict__ X, const float* __restrict__ aggs,
    const float* __restrict__ Wl, const float* __restrict__ bl,
    const float* __restrict__ Wf, const float* __restrict__ bf,
    const float* __restrict__ Wc, const float* __restrict__ bc,
    float* __restrict__ pl, float* __restrict__ pf, float* __restrict__ out)
{
    int c = blockIdx.x * 256 + threadIdx.x;
    if (c >= NCELL) return;
    const float* xr = X    + (size_t)c * D;
    const float* ar = aggs + (size_t)c * 3 * D;
    int e = blockIdx.y;

    if (e == 0) {
        // local expert: tanh([cur ; la] @ Wl + bl)
        float acc[D];
#pragma unroll
        for (int d = 0; d < D; ++d) acc[d] = bl[d];
        matvec32(xr, Wl, acc);
        matvec32(ar, Wl + D * D, acc);
#pragma unroll
        for (int d = 0; d < D; ++d) pl[(size_t)c * D + d] = fast_tanh(acc[d]);
    } else if (e == 1) {
        // functional expert: tanh([cur ; fm] @ Wf + bf)
        float acc[D];
#pragma unroll
        for (int d = 0; d < D; ++d) acc[d] = bf[d];
        matvec32(xr, Wf, acc);
        matvec32(ar + D, Wf + D * D, acc);
#pragma unroll
        for (int d = 0; d < D; ++d) pf[(size_t)c * D + d] = fast_tanh(acc[d]);
    } else {
        // distant expert: 3-step Euler; dist-half precomputed once
        float gc[D];
#pragma unroll
        for (int d = 0; d < D; ++d) gc[d] = bc[d];
        matvec32(ar + 2 * D, Wc + D * D, gc);
        float xx[D];
#pragma unroll
        for (int d = 0; d < D; ++d) xx[d] = xr[d];
        const float dt = 1.0f / 3.0f;
#pragma unroll 1
        for (int s = 0; s < 3; ++s) {
            float a2[D];
#pragma unroll
            for (int d = 0; d < D; ++d) a2[d] = gc[d];
#pragma unroll 8
            for (int j = 0; j < D; ++j) {
                float v = xx[j];
#pragma unroll
                for (int d = 0; d < D; ++d)
                    a2[d] = fmaf(v, Wc[j * D + d], a2[d]);
            }
#pragma unroll
            for (int d = 0; d < D; ++d)
                xx[d] += dt * fast_tanh(a2[d]);
        }
#pragma unroll
        for (int d = 0; d < D; ++d) out[(size_t)c * D + d] = xx[d];
    }
}

// ---------------- kernel 4: gate-weighted combine, lane per (c,d) ----------------
__global__ void __launch_bounds__(256) combine_kernel(
    const float* __restrict__ pl, const float* __restrict__ pf,
    const float* __restrict__ wgt, float* __restrict__ out)
{
    int t = blockIdx.x * 256 + threadIdx.x;
    int c = t >> 5, d = t & 31;
    if (c >= NCELL) return;
    float w0 = wgt[c * 4 + 0], w1 = wgt[c * 4 + 1], w2 = wgt[c * 4 + 2];
    size_t i = (size_t)c * D + d;
    out[i] = w0 * pl[i] + w1 * pf[i] + w2 * out[i];
}

extern "C" void kernel_launch(void* const* d_in, const int* in_sizes, int n_in,
                              void* d_out, int out_size, void* d_ws, size_t ws_size,
                              hipStream_t stream)
{
    const float* X    = (const float*)d_in[0];
    const int*   nbr  = (const int*)  d_in[1];
    const int*   tier = (const int*)  d_in[2];
    const float* Wl   = (const float*)d_in[3];
    const float* bl   = (const float*)d_in[4];
    const float* Wm   = (const float*)d_in[5];
    const float* bm   = (const float*)d_in[6];
    const float* Wf   = (const float*)d_in[7];
    const float* bf   = (const float*)d_in[8];
    const float* Wc   = (const float*)d_in[9];
    const float* bc   = (const float*)d_in[10];
    const float* Wg   = (const float*)d_in[11];
    const float* bg   = (const float*)d_in[12];
    float* out = (float*)d_out;

    // ws layout (M aliases pl: M dead after agg, pl written after agg)
    float* M    = (float*)d_ws;                       // [N][D]   16 MB  (later pl)
    float* pl   = M;
    float* aggs = M + (size_t)NCELL * D;              // [N][3][D] 48 MB
    float* pf   = aggs + (size_t)NCELL * 3 * D;       // [N][D]   16 MB
    float* wgt  = pf + (size_t)NCELL * D;             // [N][4]    2 MB

    int nt = NCELL * D;
    dim3 blk(256);
    msg_kernel<<<dim3((nt + 255) / 256), blk, 0, stream>>>(X, Wm, bm, M);
    agg_gate_kernel<<<dim3((nt + 255) / 256), blk, 0, stream>>>(
        X, M, nbr, tier, Wg, bg, aggs, wgt);
    expert_kernel<<<dim3((NCELL + 255) / 256, 3), blk, 0, stream>>>(
        X, aggs, Wl, bl, Wf, bf, Wc, bc, pl, pf, out);
    combine_kernel<<<dim3((nt + 255) / 256), blk, 0, stream>>>(pl, pf, wgt, out);
}

// Round 3
// 266.649 us; speedup vs baseline: 1.6891x; 1.0744x over previous
//
#include <hip/hip_runtime.h>
#include <hip/hip_bf16.h>
#include <math.h>

#define NCELL 125000
#define KNBR  26
#define D     32

__device__ __forceinline__ float fast_tanh(float x) {
    float e = __expf(2.0f * x);
    return 1.0f - 2.0f / (e + 1.0f);
}

// ---- kernel 1: M = tanh(X @ Wm + bm) -> bf16 ; also Xh = bf16(X) ----
// thread = (c,d); N*D = 4,000,000 = 256 * 15625 exactly (no bounds check)
__global__ void __launch_bounds__(256) msg_kernel(
    const float* __restrict__ X, const float* __restrict__ Wm,
    const float* __restrict__ bm,
    __hip_bfloat16* __restrict__ Mh, __hip_bfloat16* __restrict__ Xh)
{
    __shared__ float sX[256];
    int t = blockIdx.x * 256 + threadIdx.x;
    float v = X[t];
    sX[threadIdx.x] = v;
    Xh[t] = __float2bfloat16(v);
    __syncthreads();
    int d = t & 31;
    int base = threadIdx.x & ~31;        // this group's row in LDS
    float acc = bm[d];
#pragma unroll
    for (int j = 0; j < D; ++j)
        acc = fmaf(sX[base + j], Wm[j * D + d], acc);   // sX: uniform bcast, Wm: coalesced+hot
    Mh[t] = __float2bfloat16(fast_tanh(acc));
}

// ---- kernel 2: gather + tier means (NO gate, NO shuffles) ----
// aggs[c] = [ la | fa | da | fm ]  (f32).  8 cells per 256-thread block; 15625 blocks exact.
__global__ void __launch_bounds__(256) agg_kernel(
    const __hip_bfloat16* __restrict__ Xh, const __hip_bfloat16* __restrict__ Mh,
    const int* __restrict__ nbr, const int* __restrict__ tier,
    float* __restrict__ aggs)
{
    __shared__ int sPack[8 * KNBR];      // (idx<<2)|tier, idx<2^17
    int tid = threadIdx.x;
    int blockCell = blockIdx.x * 8;
    if (tid < 8 * KNBR) {
        int g = blockCell * KNBR + tid;  // coalesced
        sPack[tid] = (nbr[g] << 2) | tier[g];
    }
    __syncthreads();

    int grp = tid >> 5, d = tid & 31;
    int c = blockCell + grp;
    float sAll = 0.f, s0 = 0.f, s1 = 0.f, sm = 0.f;
    int n0 = 0, n1 = 0;
#pragma unroll
    for (int k = 0; k < KNBR; ++k) {
        int pk = sPack[grp * KNBR + k];  // uniform per 32-group -> broadcast ds_read
        int tt = pk & 3;
        int j  = pk >> 2;
        float x = __bfloat162float(Xh[j * D + d]);   // 64-B row gather
        bool t0 = (tt == 0), t1 = (tt == 1);
        sAll += x;
        s0 += t0 ? x : 0.f;  n0 += t0;
        s1 += t1 ? x : 0.f;  n1 += t1;
        if (t1) sm += __bfloat162float(Mh[j * D + d]);  // group-uniform branch
    }
    float s2 = sAll - s0 - s1;
    float n2 = (float)(KNBR - n0 - n1);
    float la = s0 / fmaxf((float)n0, 1.f);
    float fa = s1 / fmaxf((float)n1, 1.f);
    float da = s2 / fmaxf(n2, 1.f);
    float fm = sm / fmaxf((float)n1, 1.f);
    float* a = aggs + (size_t)c * 4 * D + d;
    a[0 * D] = la;
    a[1 * D] = fa;
    a[2 * D] = da;
    a[3 * D] = fm;
}

// acc[d] += sum_j in[j] * W[j*D+d]   (W wave-uniform -> s_load)
__device__ __forceinline__ void matvec32(const float* __restrict__ in,
                                         const float* __restrict__ W,
                                         float acc[D])
{
#pragma unroll 8
    for (int j = 0; j < D; ++j) {
        float v = in[j];
#pragma unroll
        for (int d = 0; d < D; ++d)
            acc[d] = fmaf(v, W[j * D + d], acc[d]);
    }
}

// ---- kernel 3: 4 slices via blockIdx.y: 0=local 1=func 2=cnf 3=gate ----
__global__ void __launch_bounds__(256) expert_kernel(
    const float* __restrict__ X, const float* __restrict__ aggs,
    const float* __restrict__ Wl, const float* __restrict__ bl,
    const float* __restrict__ Wf, const float* __restrict__ bf,
    const float* __restrict__ Wc, const float* __restrict__ bc,
    const float* __restrict__ Wg, const float* __restrict__ bg,
    __hip_bfloat16* __restrict__ pl, __hip_bfloat16* __restrict__ pf,
    float* __restrict__ wgt, float* __restrict__ out)
{
    int c = blockIdx.x * 256 + threadIdx.x;
    if (c >= NCELL) return;
    const float* xr = X    + (size_t)c * D;
    const float* ar = aggs + (size_t)c * 4 * D;   // la | fa | da | fm
    int e = blockIdx.y;

    if (e == 0) {                 // local: tanh([cur ; la] @ Wl + bl)
        float acc[D];
#pragma unroll
        for (int d = 0; d < D; ++d) acc[d] = bl[d];
        matvec32(xr, Wl, acc);
        matvec32(ar, Wl + D * D, acc);
#pragma unroll
        for (int d = 0; d < D; ++d)
            pl[(size_t)c * D + d] = __float2bfloat16(fast_tanh(acc[d]));
    } else if (e == 1) {          // func: tanh([cur ; fm] @ Wf + bf)
        float acc[D];
#pragma unroll
        for (int d = 0; d < D; ++d) acc[d] = bf[d];
        matvec32(xr, Wf, acc);
        matvec32(ar + 3 * D, Wf + D * D, acc);
#pragma unroll
        for (int d = 0; d < D; ++d)
            pf[(size_t)c * D + d] = __float2bfloat16(fast_tanh(acc[d]));
    } else if (e == 2) {          // cnf: 3-step Euler; dist-half precomputed
        float gc[D];
#pragma unroll
        for (int d = 0; d < D; ++d) gc[d] = bc[d];
        matvec32(ar + 2 * D, Wc + D * D, gc);
        float xx[D];
#pragma unroll
        for (int d = 0; d < D; ++d) xx[d] = xr[d];
        const float dt = 1.0f / 3.0f;
#pragma unroll 1
        for (int s = 0; s < 3; ++s) {
            float a2[D];
#pragma unroll
            for (int d = 0; d < D; ++d) a2[d] = gc[d];
#pragma unroll 8
            for (int j = 0; j < D; ++j) {
                float v = xx[j];
#pragma unroll
                for (int d = 0; d < D; ++d)
                    a2[d] = fmaf(v, Wc[j * D + d], a2[d]);
            }
#pragma unroll
            for (int d = 0; d < D; ++d)
                xx[d] += dt * fast_tanh(a2[d]);
        }
#pragma unroll
        for (int d = 0; d < D; ++d) out[(size_t)c * D + d] = xx[d];
    } else {                      // gate: softmax([cur;la;fa;da] @ Wg + bg)
        float g0 = bg[0], g1 = bg[1], g2 = bg[2];
        const float* ins[4] = { xr, ar, ar + D, ar + 2 * D };
#pragma unroll
        for (int b = 0; b < 4; ++b) {
            const float* in = ins[b];
#pragma unroll 8
            for (int j = 0; j < D; ++j) {
                float v = in[j];
                g0 = fmaf(v, Wg[(b * D + j) * 3 + 0], g0);
                g1 = fmaf(v, Wg[(b * D + j) * 3 + 1], g1);
                g2 = fmaf(v, Wg[(b * D + j) * 3 + 2], g2);
            }
        }
        float mx = fmaxf(g0, fmaxf(g1, g2));
        float e0 = __expf(g0 - mx), e1 = __expf(g1 - mx), e2 = __expf(g2 - mx);
        float inv = 1.f / (e0 + e1 + e2);
        float4 w = make_float4(e0 * inv, e1 * inv, e2 * inv, 0.f);
        *(float4*)(wgt + (size_t)c * 4) = w;
    }
}

// ---- kernel 4: combine ----
__global__ void __launch_bounds__(256) combine_kernel(
    const __hip_bfloat16* __restrict__ pl, const __hip_bfloat16* __restrict__ pf,
    const float* __restrict__ wgt, float* __restrict__ out)
{
    int t = blockIdx.x * 256 + threadIdx.x;
    int c = t >> 5;
    float w0 = wgt[c * 4 + 0], w1 = wgt[c * 4 + 1], w2 = wgt[c * 4 + 2];
    out[t] = w0 * __bfloat162float(pl[t]) + w1 * __bfloat162float(pf[t]) + w2 * out[t];
}

extern "C" void kernel_launch(void* const* d_in, const int* in_sizes, int n_in,
                              void* d_out, int out_size, void* d_ws, size_t ws_size,
                              hipStream_t stream)
{
    const float* X    = (const float*)d_in[0];
    const int*   nbr  = (const int*)  d_in[1];
    const int*   tier = (const int*)  d_in[2];
    const float* Wl   = (const float*)d_in[3];
    const float* bl   = (const float*)d_in[4];
    const float* Wm   = (const float*)d_in[5];
    const float* bm   = (const float*)d_in[6];
    const float* Wf   = (const float*)d_in[7];
    const float* bf   = (const float*)d_in[8];
    const float* Wc   = (const float*)d_in[9];
    const float* bc   = (const float*)d_in[10];
    const float* Wg   = (const float*)d_in[11];
    const float* bg   = (const float*)d_in[12];
    float* out = (float*)d_out;

    const size_t ND = (size_t)NCELL * D;
    // ws layout: [Mh bf16 8MB | Xh bf16 8MB] (dead after agg; pl/pf alias it)
    //            [aggs f32 64MB] [wgt 2MB]
    __hip_bfloat16* Mh = (__hip_bfloat16*)d_ws;
    __hip_bfloat16* Xh = Mh + ND;
    __hip_bfloat16* pl = Mh;                       // alias Mh (8MB)
    __hip_bfloat16* pf = Xh;                       // alias Xh (8MB)
    float* aggs = (float*)(Xh + ND);               // N*4*D f32
    float* wgt  = aggs + (size_t)NCELL * 4 * D;    // N*4 f32

    dim3 blk(256);
    int ndBlocks = (int)(ND / 256);                // 15625 exact
    msg_kernel<<<dim3(ndBlocks), blk, 0, stream>>>(X, Wm, bm, Mh, Xh);
    agg_kernel<<<dim3(NCELL / 8), blk, 0, stream>>>(Xh, Mh, nbr, tier, aggs);
    expert_kernel<<<dim3((NCELL + 255) / 256, 4), blk, 0, stream>>>(
        X, aggs, Wl, bl, Wf, bf, Wc, bc, Wg, bg, pl, pf, wgt, out);
    combine_kernel<<<dim3(ndBlocks), blk, 0, stream>>>(pl, pf, wgt, out);
}

// Round 4
// 243.305 us; speedup vs baseline: 1.8511x; 1.0959x over previous
//
#include <hip/hip_runtime.h>
#include <hip/hip_bf16.h>
#include <math.h>

#define NCELL 125000
#define KNBR  26
#define D     32
#define CB    128   // cells per block in moe_kernel

__device__ __forceinline__ float fast_tanh(float x) {
    float e = __expf(2.0f * x);
    return 1.0f - 2.0f / (e + 1.0f);
}
__device__ __forceinline__ float bf2f(unsigned int h) {
    return __uint_as_float(h << 16);
}
// decode a 32-elem bf16 row (64B) into f32
__device__ __forceinline__ void load_row_bf16(const unsigned short* __restrict__ p,
                                              float* __restrict__ dst) {
#pragma unroll
    for (int k = 0; k < 4; ++k) {
        uint4 v = *(const uint4*)(p + k * 8);
        dst[k*8+0] = bf2f(v.x & 0xffff); dst[k*8+1] = bf2f(v.x >> 16);
        dst[k*8+2] = bf2f(v.y & 0xffff); dst[k*8+3] = bf2f(v.y >> 16);
        dst[k*8+4] = bf2f(v.z & 0xffff); dst[k*8+5] = bf2f(v.z >> 16);
        dst[k*8+6] = bf2f(v.w & 0xffff); dst[k*8+7] = bf2f(v.w >> 16);
    }
}

// ---- kernel 1: M = tanh(X @ Wm + bm) -> bf16 ; Xh = bf16(X) ----
__global__ void __launch_bounds__(256) msg_kernel(
    const float* __restrict__ X, const float* __restrict__ Wm,
    const float* __restrict__ bm,
    __hip_bfloat16* __restrict__ Mh, __hip_bfloat16* __restrict__ Xh)
{
    __shared__ float sX[256];
    int t = blockIdx.x * 256 + threadIdx.x;
    float v = X[t];
    sX[threadIdx.x] = v;
    Xh[t] = __float2bfloat16(v);
    __syncthreads();
    int d = t & 31;
    int base = threadIdx.x & ~31;
    float acc = bm[d];
#pragma unroll
    for (int j = 0; j < D; ++j)
        acc = fmaf(sX[base + j], Wm[j * D + d], acc);
    Mh[t] = __float2bfloat16(fast_tanh(acc));
}

// ---- kernel 2: gather + tier means -> aggs bf16 [N][4][D] = la|fa|da|fm ----
__global__ void __launch_bounds__(256) agg_kernel(
    const __hip_bfloat16* __restrict__ Xh, const __hip_bfloat16* __restrict__ Mh,
    const int* __restrict__ nbr, const int* __restrict__ tier,
    __hip_bfloat16* __restrict__ aggs)
{
    __shared__ int sPack[8 * KNBR];
    int tid = threadIdx.x;
    int blockCell = blockIdx.x * 8;
    if (tid < 8 * KNBR) {
        int g = blockCell * KNBR + tid;
        sPack[tid] = (nbr[g] << 2) | tier[g];
    }
    __syncthreads();

    int grp = tid >> 5, d = tid & 31;
    int c = blockCell + grp;
    float sAll = 0.f, s0 = 0.f, s1 = 0.f, sm = 0.f;
    int n0 = 0, n1 = 0;
#pragma unroll
    for (int k = 0; k < KNBR; ++k) {
        int pk = sPack[grp * KNBR + k];      // uniform per 32-group
        int tt = pk & 3;
        int j  = pk >> 2;
        float x = __bfloat162float(Xh[j * D + d]);
        bool t0 = (tt == 0), t1 = (tt == 1);
        sAll += x;
        s0 += t0 ? x : 0.f;  n0 += t0;
        s1 += t1 ? x : 0.f;  n1 += t1;
        if (t1) sm += __bfloat162float(Mh[j * D + d]);
    }
    float s2 = sAll - s0 - s1;
    float n2 = (float)(KNBR - n0 - n1);
    __hip_bfloat16* a = aggs + (size_t)c * 4 * D + d;
    a[0 * D] = __float2bfloat16(s0 / fmaxf((float)n0, 1.f));
    a[1 * D] = __float2bfloat16(s1 / fmaxf((float)n1, 1.f));
    a[2 * D] = __float2bfloat16(s2 / fmaxf(n2, 1.f));
    a[3 * D] = __float2bfloat16(sm / fmaxf((float)n1, 1.f));
}

// ---- kernel 3: fused experts + gate + combine ----
// 256 threads = 128 cells x 2 roles. half0: gate+CNF. half1: local+func.
// sX: XOR-swizzled f32 rows (conflict-free b128); reused for xx exchange and
// output transpose. W accesses are wave-uniform -> s_load (SGPR operands).
__global__ void __launch_bounds__(256) moe_kernel(
    const float* __restrict__ X, const unsigned short* __restrict__ aggs,
    const float* __restrict__ Wl, const float* __restrict__ bl,
    const float* __restrict__ Wf, const float* __restrict__ bfv,
    const float* __restrict__ Wc, const float* __restrict__ bc,
    const float* __restrict__ Wg, const float* __restrict__ bg,
    float* __restrict__ out)
{
    __shared__ float sX[CB * D];
    __shared__ float sW[CB * 4];
    int tid  = threadIdx.x;
    int base = blockIdx.x * CB;
    int limit = (NCELL - base) * D; if (limit > CB * D) limit = CB * D;

    // stage X coalesced -> swizzled LDS
    const float4* gX = (const float4*)(X + (size_t)base * D);
#pragma unroll
    for (int k = 0; k < (CB * D / 4) / 256; ++k) {   // 4 iters
        int g = tid + k * 256;
        if (g * 4 < limit) {
            float4 v = gX[g];
            int cc = g >> 3;
            int j0 = (g & 7) << 2;
            *(float4*)&sX[cc * D + (j0 ^ ((cc & 7) << 2))] = v;
        }
    }
    __syncthreads();

    int half = tid >> 7;
    int cc   = tid & 127;
    int c    = base + cc;
    bool active = (c < NCELL);

    float cur[D];
    if (active) {
#pragma unroll
        for (int j4 = 0; j4 < 8; ++j4) {
            float4 v = *(float4*)&sX[cc * D + ((j4 << 2) ^ ((cc & 7) << 2))];
            cur[j4*4+0] = v.x; cur[j4*4+1] = v.y; cur[j4*4+2] = v.z; cur[j4*4+3] = v.w;
        }
    }
    __syncthreads();   // all cur reads done before half0 overwrites sX

    float lo[D], fo[D];          // half1 results
    if (active) {
        const unsigned short* ag = aggs + (size_t)c * 4 * D;
        if (half == 0) {
            // ---- gate ----
            float g0 = bg[0], g1 = bg[1], g2 = bg[2];
#pragma unroll 8
            for (int j = 0; j < D; ++j) {
                float v = cur[j];
                g0 = fmaf(v, Wg[j*3+0], g0); g1 = fmaf(v, Wg[j*3+1], g1); g2 = fmaf(v, Wg[j*3+2], g2);
            }
            float tmp[D];
            load_row_bf16(ag + 0 * D, tmp);          // la
#pragma unroll 8
            for (int j = 0; j < D; ++j) {
                float v = tmp[j];
                g0 = fmaf(v, Wg[(D+j)*3+0], g0); g1 = fmaf(v, Wg[(D+j)*3+1], g1); g2 = fmaf(v, Wg[(D+j)*3+2], g2);
            }
            load_row_bf16(ag + 1 * D, tmp);          // fa
#pragma unroll 8
            for (int j = 0; j < D; ++j) {
                float v = tmp[j];
                g0 = fmaf(v, Wg[(2*D+j)*3+0], g0); g1 = fmaf(v, Wg[(2*D+j)*3+1], g1); g2 = fmaf(v, Wg[(2*D+j)*3+2], g2);
            }
            float da[D];
            load_row_bf16(ag + 2 * D, da);           // da
#pragma unroll 8
            for (int j = 0; j < D; ++j) {
                float v = da[j];
                g0 = fmaf(v, Wg[(3*D+j)*3+0], g0); g1 = fmaf(v, Wg[(3*D+j)*3+1], g1); g2 = fmaf(v, Wg[(3*D+j)*3+2], g2);
            }
            float mx = fmaxf(g0, fmaxf(g1, g2));
            float e0 = __expf(g0 - mx), e1 = __expf(g1 - mx), e2 = __expf(g2 - mx);
            float inv = 1.f / (e0 + e1 + e2);
            *(float4*)&sW[cc * 4] = make_float4(e0 * inv, e1 * inv, e2 * inv, 0.f);

            // ---- CNF: gc = bc + da @ Wc[32:64] ----
            float gc[D];
#pragma unroll
            for (int d = 0; d < D; ++d) gc[d] = bc[d];
#pragma unroll 8
            for (int j = 0; j < D; ++j) {
                float v = da[j];
#pragma unroll
                for (int d = 0; d < D; ++d) gc[d] = fmaf(v, Wc[(D + j) * D + d], gc[d]);
            }
            float xx[D];
#pragma unroll
            for (int d = 0; d < D; ++d) xx[d] = cur[d];
            const float dt = 1.0f / 3.0f;
#pragma unroll 1
            for (int s = 0; s < 3; ++s) {
                float a2[D];
#pragma unroll
                for (int d = 0; d < D; ++d) a2[d] = gc[d];
#pragma unroll 8
                for (int j = 0; j < D; ++j) {
                    float v = xx[j];
#pragma unroll
                    for (int d = 0; d < D; ++d) a2[d] = fmaf(v, Wc[j * D + d], a2[d]);
                }
#pragma unroll
                for (int d = 0; d < D; ++d) xx[d] += dt * fast_tanh(a2[d]);
            }
            // write xx back into sX (swizzled) for half1
#pragma unroll
            for (int j4 = 0; j4 < 8; ++j4) {
                float4 v = make_float4(xx[j4*4+0], xx[j4*4+1], xx[j4*4+2], xx[j4*4+3]);
                *(float4*)&sX[cc * D + ((j4 << 2) ^ ((cc & 7) << 2))] = v;
            }
        } else {
            // ---- local + func: shared cur pass, then row passes ----
            float accL[D], accF[D];
#pragma unroll
            for (int d = 0; d < D; ++d) { accL[d] = bl[d]; accF[d] = bfv[d]; }
#pragma unroll 8
            for (int j = 0; j < D; ++j) {
                float v = cur[j];
#pragma unroll
                for (int d = 0; d < D; ++d) {
                    accL[d] = fmaf(v, Wl[j * D + d], accL[d]);
                    accF[d] = fmaf(v, Wf[j * D + d], accF[d]);
                }
            }
            float tmp[D];
            load_row_bf16(ag + 0 * D, tmp);          // la
#pragma unroll 8
            for (int j = 0; j < D; ++j) {
                float v = tmp[j];
#pragma unroll
                for (int d = 0; d < D; ++d) accL[d] = fmaf(v, Wl[(D + j) * D + d], accL[d]);
            }
            load_row_bf16(ag + 3 * D, tmp);          // fm
#pragma unroll 8
            for (int j = 0; j < D; ++j) {
                float v = tmp[j];
#pragma unroll
                for (int d = 0; d < D; ++d) accF[d] = fmaf(v, Wf[(D + j) * D + d], accF[d]);
            }
#pragma unroll
            for (int d = 0; d < D; ++d) { lo[d] = fast_tanh(accL[d]); fo[d] = fast_tanh(accF[d]); }
        }
    }
    __syncthreads();   // xx + w visible

    if (active && half == 1) {
        float4 wv = *(float4*)&sW[cc * 4];
        float o[D];
#pragma unroll
        for (int j4 = 0; j4 < 8; ++j4) {
            float4 v = *(float4*)&sX[cc * D + ((j4 << 2) ^ ((cc & 7) << 2))];  // xx
            o[j4*4+0] = wv.x * lo[j4*4+0] + wv.y * fo[j4*4+0] + wv.z * v.x;
            o[j4*4+1] = wv.x * lo[j4*4+1] + wv.y * fo[j4*4+1] + wv.z * v.y;
            o[j4*4+2] = wv.x * lo[j4*4+2] + wv.y * fo[j4*4+2] + wv.z * v.z;
            o[j4*4+3] = wv.x * lo[j4*4+3] + wv.y * fo[j4*4+3] + wv.z * v.w;
        }
#pragma unroll
        for (int j4 = 0; j4 < 8; ++j4)     // own row: read above, write now
            *(float4*)&sX[cc * D + ((j4 << 2) ^ ((cc & 7) << 2))] =
                make_float4(o[j4*4+0], o[j4*4+1], o[j4*4+2], o[j4*4+3]);
    }
    __syncthreads();

    // coalesced store via LDS transpose
    float4* gO = (float4*)(out + (size_t)base * D);
#pragma unroll
    for (int k = 0; k < (CB * D / 4) / 256; ++k) {
        int g = tid + k * 256;
        if (g * 4 < limit) {
            int cc2 = g >> 3;
            int j0  = (g & 7) << 2;
            gO[g] = *(float4*)&sX[cc2 * D + (j0 ^ ((cc2 & 7) << 2))];
        }
    }
}

extern "C" void kernel_launch(void* const* d_in, const int* in_sizes, int n_in,
                              void* d_out, int out_size, void* d_ws, size_t ws_size,
                              hipStream_t stream)
{
    const float* X    = (const float*)d_in[0];
    const int*   nbr  = (const int*)  d_in[1];
    const int*   tier = (const int*)  d_in[2];
    const float* Wl   = (const float*)d_in[3];
    const float* bl   = (const float*)d_in[4];
    const float* Wm   = (const float*)d_in[5];
    const float* bm   = (const float*)d_in[6];
    const float* Wf   = (const float*)d_in[7];
    const float* bf   = (const float*)d_in[8];
    const float* Wc   = (const float*)d_in[9];
    const float* bc   = (const float*)d_in[10];
    const float* Wg   = (const float*)d_in[11];
    const float* bg   = (const float*)d_in[12];
    float* out = (float*)d_out;

    const size_t ND = (size_t)NCELL * D;
    __hip_bfloat16* Mh   = (__hip_bfloat16*)d_ws;      // 8 MB
    __hip_bfloat16* Xh   = Mh + ND;                    // 8 MB
    __hip_bfloat16* aggs = Xh + ND;                    // N*4*D bf16 = 32 MB

    dim3 blk(256);
    msg_kernel<<<dim3(ND / 256), blk, 0, stream>>>(X, Wm, bm, Mh, Xh);
    agg_kernel<<<dim3(NCELL / 8), blk, 0, stream>>>(Xh, Mh, nbr, tier, aggs);
    moe_kernel<<<dim3((NCELL + CB - 1) / CB), blk, 0, stream>>>(
        X, (const unsigned short*)aggs, Wl, bl, Wf, bf, Wc, bc, Wg, bg, out);
}